// Round 3
// baseline (111.436 us; speedup 1.0000x reference)
//
#include <hip/hip_runtime.h>
#include <math.h>

#define N 2
#define C 19
#define H 512
#define W 512
#define PADC 50
#define WC 412
#define S 8192
#define CP 20            // padded channels (16B-aligned rows)
#define TS 4             // s-rows per thread (register tile)
#define BS 256           // threads per block
#define SROWS (TS * BS)  // 1024 s-rows per block
#define TT 128           // t rows staged in LDS per iteration
#define EPSF 1e-6f

// P[n][s][c] = output[n, c, 50 + sample[s]/412, 50 + sample[s]%412]
// one 32-lane group per (n,s): lane c loads channel c (19 parallel scattered
// loads, latency hidden by 8192 waves); 80B row writes are contiguous.
__global__ void gather_k(const float* __restrict__ out4d,
                         const int* __restrict__ sample,
                         float* __restrict__ P) {
    int idx = blockIdx.x * blockDim.x + threadIdx.x;   // 0 .. N*S*32-1
    int lane = idx & 31;
    int ns = idx >> 5;                                  // n*S + s
    int nn = ns >> 13;                                  // / S
    int s  = ns & (S - 1);
    int smp = sample[s];
    int row = smp / WC;
    int col = smp - row * WC;
    const float* base = out4d + ((size_t)nn * C) * H * W
                      + (size_t)(PADC + row) * W + (PADC + col);
    float* p = P + (size_t)ns * CP;
    if (lane < C)       p[lane] = base[(size_t)lane * (H * W)];
    else if (lane == C) p[C] = 0.f;
}

// per (n, s-tile, t-chunk): best dot + (lowest) t index over the chunk.
// Each thread owns TS s-rows in registers; t-rows staged in LDS, consumed
// through a register double-buffer (loop-carried -> no interchange).
__global__ __launch_bounds__(256) void argmax_k(const float* __restrict__ P,
                                                float* __restrict__ pmax,
                                                int* __restrict__ pidx,
                                                int nchunk) {
    __shared__ float tile[TT * CP];   // 10 KiB
    int b = blockIdx.x;
    int chunk = b % nchunk;
    int stile = (b / nchunk) % (S / SROWS);
    int nn = b / (nchunk * (S / SROWS));
    int tid = threadIdx.x;
    int chunkLen = S / nchunk;
    int t0 = chunk * chunkLen;
    const float* Pn = P + (size_t)nn * S * CP;

    // TS s-rows, register-resident as 5 float4 each
    float4 a[TS][5];
    int srow[TS];
    #pragma unroll
    for (int i = 0; i < TS; ++i) {
        srow[i] = stile * SROWS + i * BS + tid;
        const float4* r = (const float4*)(Pn + (size_t)srow[i] * CP);
        a[i][0] = r[0]; a[i][1] = r[1]; a[i][2] = r[2];
        a[i][3] = r[3]; a[i][4] = r[4];
    }

    float best[TS];
    int   bi[TS];
    #pragma unroll
    for (int i = 0; i < TS; ++i) { best[i] = -INFINITY; bi[i] = t0; }

    for (int tb = 0; tb < chunkLen; tb += TT) {
        // cooperative stage: TT rows * CP floats = 640 contiguous float4
        const float4* src = (const float4*)(Pn + (size_t)(t0 + tb) * CP);
        float4* dst = (float4*)tile;
        #pragma unroll
        for (int f = 0; f < 3; ++f) {
            int k = f * BS + tid;
            if (k < TT * CP / 4) dst[k] = src[k];
        }
        __syncthreads();

        // register double-buffer over t-rows
        float4 b0, b1, b2, b3, b4;
        {
            const float4* r0 = (const float4*)tile;
            b0 = r0[0]; b1 = r0[1]; b2 = r0[2]; b3 = r0[3]; b4 = r0[4];
        }
        #pragma unroll 2
        for (int tt = 0; tt < TT; ++tt) {
            int tn = (tt + 1 < TT) ? tt + 1 : TT - 1;
            const float4* nx = (const float4*)(tile + tn * CP);
            float4 n0 = nx[0], n1 = nx[1], n2 = nx[2], n3 = nx[3], n4 = nx[4];
            int t = t0 + tb + tt;
            #pragma unroll
            for (int i = 0; i < TS; ++i) {
                // two independent sub-chains -> dep latency hidden
                float d0 = a[i][0].x * b0.x;
                d0 = fmaf(a[i][0].y, b0.y, d0);
                d0 = fmaf(a[i][0].z, b0.z, d0);
                d0 = fmaf(a[i][0].w, b0.w, d0);
                d0 = fmaf(a[i][1].x, b1.x, d0);
                d0 = fmaf(a[i][1].y, b1.y, d0);
                d0 = fmaf(a[i][1].z, b1.z, d0);
                d0 = fmaf(a[i][1].w, b1.w, d0);
                d0 = fmaf(a[i][2].x, b2.x, d0);
                d0 = fmaf(a[i][2].y, b2.y, d0);
                float d1 = a[i][2].z * b2.z;
                d1 = fmaf(a[i][2].w, b2.w, d1);
                d1 = fmaf(a[i][3].x, b3.x, d1);
                d1 = fmaf(a[i][3].y, b3.y, d1);
                d1 = fmaf(a[i][3].z, b3.z, d1);
                d1 = fmaf(a[i][3].w, b3.w, d1);
                d1 = fmaf(a[i][4].x, b4.x, d1);
                d1 = fmaf(a[i][4].y, b4.y, d1);
                d1 = fmaf(a[i][4].z, b4.z, d1);
                float d = d0 + d1;
                if (d > best[i]) { best[i] = d; bi[i] = t; }  // strict >: first-max
            }
            b0 = n0; b1 = n1; b2 = n2; b3 = n3; b4 = n4;
        }
        __syncthreads();
    }
    #pragma unroll
    for (int i = 0; i < TS; ++i) {
        pmax[((size_t)nn * nchunk + chunk) * S + srow[i]] = best[i];
        pidx[((size_t)nn * nchunk + chunk) * S + srow[i]] = bi[i];
    }
}

// merge chunk partials -> ind, then the 19 loss terms; fixed-order block reduce
__global__ __launch_bounds__(256) void loss_k(const float* __restrict__ P,
                                              const float* __restrict__ pmax,
                                              const int* __restrict__ pidx,
                                              float* __restrict__ bsum,
                                              int nchunk) {
    __shared__ float red[256];
    int idx = blockIdx.x * 256 + threadIdx.x;   // 0 .. N*S-1
    int nn = idx / S;
    int s  = idx - nn * S;

    const float* pm = pmax + (size_t)nn * nchunk * S + s;
    const int*   pi = pidx + (size_t)nn * nchunk * S + s;
    float best = pm[0];
    int bi = pi[0];
    for (int k = 1; k < nchunk; ++k) {
        float v = pm[(size_t)k * S];
        int   t = pi[(size_t)k * S];
        if (v > best) { best = v; bi = t; }   // ascending chunks: first-max wins
    }

    const float* Pn    = P + (size_t)nn * S * CP;
    const float* nrow  = Pn + (size_t)bi * CP;
    const float* ps    = Pn + (size_t)s  * CP;
    float acc = 0.f;
    #pragma unroll
    for (int c = 0; c < C; ++c) acc -= nrow[c] * logf(ps[c] + EPSF);

    red[threadIdx.x] = acc;
    __syncthreads();
    for (int off = 128; off > 0; off >>= 1) {
        if (threadIdx.x < off) red[threadIdx.x] += red[threadIdx.x + off];
        __syncthreads();
    }
    if (threadIdx.x == 0) bsum[blockIdx.x] = red[0];
}

__global__ void final_k(const float* __restrict__ bsum, float* __restrict__ out) {
    float t = 0.f;
    for (int i = 0; i < (N * S) / 256; ++i) t += bsum[i];   // fixed order
    out[0] = t / (float)(N * S * C);
}

extern "C" void kernel_launch(void* const* d_in, const int* in_sizes, int n_in,
                              void* d_out, int out_size, void* d_ws, size_t ws_size,
                              hipStream_t stream) {
    const float* out4d  = (const float*)d_in[0];
    const int*   sample = (const int*)d_in[1];

    // pick the largest chunk count whose partials fit the workspace
    size_t pbytes = (size_t)N * S * CP * 4;
    int nchunk = 64;
    while (nchunk > 8) {
        size_t need = pbytes + (size_t)N * nchunk * S * 8 + 1024;
        if (need <= ws_size) break;
        nchunk >>= 1;
    }

    float* P    = (float*)d_ws;                               // N*S*CP floats
    float* pmax = P + (size_t)N * S * CP;                     // N*nchunk*S floats
    int*   pidx = (int*)(pmax + (size_t)N * nchunk * S);      // N*nchunk*S ints
    float* bsum = (float*)(pidx + (size_t)N * nchunk * S);    // 64 floats
    float* outp = (float*)d_out;

    gather_k<<<(N * S * 32) / 256, 256, 0, stream>>>(out4d, sample, P);
    argmax_k<<<N * nchunk * (S / SROWS), 256, 0, stream>>>(P, pmax, pidx, nchunk);
    loss_k<<<(N * S) / 256, 256, 0, stream>>>(P, pmax, pidx, bsum, nchunk);
    final_k<<<1, 1, 0, stream>>>(bsum, outp);
}

// Round 4
// 98.494 us; speedup vs baseline: 1.1314x; 1.1314x over previous
//
#include <hip/hip_runtime.h>
#include <math.h>

#define N 2
#define C 19
#define H 512
#define W 512
#define PADC 50
#define WC 412
#define S 8192
#define CP 20            // padded channels (16B-aligned rows)
#define TS 4             // s-rows per thread (register tile)
#define BS 256           // threads per block
#define SROWS (TS * BS)  // 1024 s-rows per block
#define EPSF 1e-6f

// P[n][s][c] = output[n, c, 50 + sample[s]/412, 50 + sample[s]%412]
// one 32-lane group per (n,s): lane c loads channel c; 80B row writes contiguous.
__global__ void gather_k(const float* __restrict__ out4d,
                         const int* __restrict__ sample,
                         float* __restrict__ P) {
    int idx = blockIdx.x * blockDim.x + threadIdx.x;   // 0 .. N*S*32-1
    int lane = idx & 31;
    int ns = idx >> 5;                                  // n*S + s
    int nn = ns >> 13;                                  // / S
    int s  = ns & (S - 1);
    int smp = sample[s];
    int row = smp / WC;
    int col = smp - row * WC;
    const float* base = out4d + ((size_t)nn * C) * H * W
                      + (size_t)(PADC + row) * W + (PADC + col);
    float* p = P + (size_t)ns * CP;
    if (lane < C)       p[lane] = base[(size_t)lane * (H * W)];
    else if (lane == C) p[C] = 0.f;
}

// per (n, s-tile, t-chunk): best dot + (lowest) t index over the chunk.
// s-rows pinned in VGPRs (asm fence); t-rows read wave-uniform -> SGPRs
// (s_load) and consumed as the scalar operand of v_fma. No LDS, no barriers.
__global__ __launch_bounds__(256, 3) void argmax_k(const float* __restrict__ P,
                                                   float* __restrict__ pmax,
                                                   int* __restrict__ pidx,
                                                   int nchunk) {
    int b = blockIdx.x;
    int chunk = b % nchunk;
    int stile = (b / nchunk) % (S / SROWS);
    int nn = b / (nchunk * (S / SROWS));
    int tid = threadIdx.x;
    int chunkLen = S / nchunk;
    int t0 = chunk * chunkLen;
    const float* Pn = P + (size_t)nn * S * CP;

    // TS s-rows -> 76 named registers, pinned via asm fence
    float av[TS][C];
    int srow[TS];
    #pragma unroll
    for (int i = 0; i < TS; ++i) {
        srow[i] = stile * SROWS + i * BS + tid;
        const float4* r = (const float4*)(Pn + (size_t)srow[i] * CP);
        float4 a0 = r[0], a1 = r[1], a2 = r[2], a3 = r[3], a4 = r[4];
        av[i][0]=a0.x;  av[i][1]=a0.y;  av[i][2]=a0.z;  av[i][3]=a0.w;
        av[i][4]=a1.x;  av[i][5]=a1.y;  av[i][6]=a1.z;  av[i][7]=a1.w;
        av[i][8]=a2.x;  av[i][9]=a2.y;  av[i][10]=a2.z; av[i][11]=a2.w;
        av[i][12]=a3.x; av[i][13]=a3.y; av[i][14]=a3.z; av[i][15]=a3.w;
        av[i][16]=a4.x; av[i][17]=a4.y; av[i][18]=a4.z;
        asm volatile("" : "+v"(av[i][0]), "+v"(av[i][1]), "+v"(av[i][2]),
                          "+v"(av[i][3]), "+v"(av[i][4]), "+v"(av[i][5]),
                          "+v"(av[i][6]), "+v"(av[i][7]), "+v"(av[i][8]),
                          "+v"(av[i][9]), "+v"(av[i][10]), "+v"(av[i][11]),
                          "+v"(av[i][12]), "+v"(av[i][13]), "+v"(av[i][14]),
                          "+v"(av[i][15]), "+v"(av[i][16]), "+v"(av[i][17]),
                          "+v"(av[i][18]));
    }

    float best[TS];
    int   bi[TS];
    #pragma unroll
    for (int i = 0; i < TS; ++i) { best[i] = -INFINITY; bi[i] = t0; }

    const float* Bbase = Pn + (size_t)t0 * CP;
    #pragma unroll 2
    for (int tt = 0; tt < chunkLen; ++tt) {
        // wave-uniform address -> scalar loads into SGPRs
        const float4* br = (const float4*)(Bbase + (size_t)tt * CP);
        float4 q0 = br[0], q1 = br[1], q2 = br[2], q3 = br[3], q4 = br[4];
        float bv[C] = {q0.x,q0.y,q0.z,q0.w, q1.x,q1.y,q1.z,q1.w,
                       q2.x,q2.y,q2.z,q2.w, q3.x,q3.y,q3.z,q3.w,
                       q4.x,q4.y,q4.z};
        int t = t0 + tt;
        #pragma unroll
        for (int i = 0; i < TS; ++i) {
            // two independent sub-chains -> dep latency hidden
            float d0 = av[i][0] * bv[0];
            d0 = fmaf(av[i][1], bv[1], d0);
            d0 = fmaf(av[i][2], bv[2], d0);
            d0 = fmaf(av[i][3], bv[3], d0);
            d0 = fmaf(av[i][4], bv[4], d0);
            d0 = fmaf(av[i][5], bv[5], d0);
            d0 = fmaf(av[i][6], bv[6], d0);
            d0 = fmaf(av[i][7], bv[7], d0);
            d0 = fmaf(av[i][8], bv[8], d0);
            d0 = fmaf(av[i][9], bv[9], d0);
            float d1 = av[i][10] * bv[10];
            d1 = fmaf(av[i][11], bv[11], d1);
            d1 = fmaf(av[i][12], bv[12], d1);
            d1 = fmaf(av[i][13], bv[13], d1);
            d1 = fmaf(av[i][14], bv[14], d1);
            d1 = fmaf(av[i][15], bv[15], d1);
            d1 = fmaf(av[i][16], bv[16], d1);
            d1 = fmaf(av[i][17], bv[17], d1);
            d1 = fmaf(av[i][18], bv[18], d1);
            float d = d0 + d1;
            if (d > best[i]) { best[i] = d; bi[i] = t; }  // strict >: first-max
        }
    }
    #pragma unroll
    for (int i = 0; i < TS; ++i) {
        pmax[((size_t)nn * nchunk + chunk) * S + srow[i]] = best[i];
        pidx[((size_t)nn * nchunk + chunk) * S + srow[i]] = bi[i];
    }
}

// merge chunk partials -> ind, then the 19 loss terms; fixed-order block reduce
__global__ __launch_bounds__(256) void loss_k(const float* __restrict__ P,
                                              const float* __restrict__ pmax,
                                              const int* __restrict__ pidx,
                                              float* __restrict__ bsum,
                                              int nchunk) {
    __shared__ float red[256];
    int idx = blockIdx.x * 256 + threadIdx.x;   // 0 .. N*S-1
    int nn = idx / S;
    int s  = idx - nn * S;

    const float* pm = pmax + (size_t)nn * nchunk * S + s;
    const int*   pi = pidx + (size_t)nn * nchunk * S + s;
    float best = pm[0];
    int bi = pi[0];
    for (int k = 1; k < nchunk; ++k) {
        float v = pm[(size_t)k * S];
        int   t = pi[(size_t)k * S];
        if (v > best) { best = v; bi = t; }   // ascending chunks: first-max wins
    }

    const float* Pn    = P + (size_t)nn * S * CP;
    const float* nrow  = Pn + (size_t)bi * CP;
    const float* ps    = Pn + (size_t)s  * CP;
    float acc = 0.f;
    #pragma unroll
    for (int c = 0; c < C; ++c) acc -= nrow[c] * logf(ps[c] + EPSF);

    red[threadIdx.x] = acc;
    __syncthreads();
    for (int off = 128; off > 0; off >>= 1) {
        if (threadIdx.x < off) red[threadIdx.x] += red[threadIdx.x + off];
        __syncthreads();
    }
    if (threadIdx.x == 0) bsum[blockIdx.x] = red[0];
}

__global__ void final_k(const float* __restrict__ bsum, float* __restrict__ out) {
    float t = 0.f;
    for (int i = 0; i < (N * S) / 256; ++i) t += bsum[i];   // fixed order
    out[0] = t / (float)(N * S * C);
}

extern "C" void kernel_launch(void* const* d_in, const int* in_sizes, int n_in,
                              void* d_out, int out_size, void* d_ws, size_t ws_size,
                              hipStream_t stream) {
    const float* out4d  = (const float*)d_in[0];
    const int*   sample = (const int*)d_in[1];

    // pick the largest chunk count whose partials fit the workspace
    size_t pbytes = (size_t)N * S * CP * 4;
    int nchunk = 64;
    while (nchunk > 8) {
        size_t need = pbytes + (size_t)N * nchunk * S * 8 + 1024;
        if (need <= ws_size) break;
        nchunk >>= 1;
    }

    float* P    = (float*)d_ws;                               // N*S*CP floats
    float* pmax = P + (size_t)N * S * CP;                     // N*nchunk*S floats
    int*   pidx = (int*)(pmax + (size_t)N * nchunk * S);      // N*nchunk*S ints
    float* bsum = (float*)(pidx + (size_t)N * nchunk * S);    // 64 floats
    float* outp = (float*)d_out;

    gather_k<<<(N * S * 32) / 256, 256, 0, stream>>>(out4d, sample, P);
    argmax_k<<<N * nchunk * (S / SROWS), 256, 0, stream>>>(P, pmax, pidx, nchunk);
    loss_k<<<(N * S) / 256, 256, 0, stream>>>(P, pmax, pidx, bsum, nchunk);
    final_k<<<1, 1, 0, stream>>>(bsum, outp);
}

// Round 5
// 52.987 us; speedup vs baseline: 2.1031x; 1.8588x over previous
//
#include <hip/hip_runtime.h>
#include <math.h>

#define N 2
#define C 19
#define H 512
#define W 512
#define PADC 50
#define WC 412
#define S 8192
#define CP 20            // fp32 P row pitch (floats)
#define XP 64            // bf16 X row pitch (ushorts): hi 0..31, lo 32..63
#define NCHUNK 8
#define CHUNKT 1024      // t per chunk
#define TTS 128          // t rows per LDS stage
#define LPITCH 72        // ushorts per LDS row (144 B)
#define EPSF 1e-6f

typedef __attribute__((ext_vector_type(8))) short short8;
typedef __attribute__((ext_vector_type(16))) float f32x16;

__device__ __forceinline__ unsigned short f2bf_rne(float x) {
    unsigned u = __float_as_uint(x);
    unsigned r = (u + 0x7FFFu + ((u >> 16) & 1u)) >> 16;
    return (unsigned short)r;
}
__device__ __forceinline__ float bf2f(unsigned short h) {
    return __uint_as_float(((unsigned)h) << 16);
}

// P32[n][s][c] fp32 (for loss); X[n][s][0..31]=hi bf16 (19..31 zero),
// X[n][s][32..63]=lo bf16 residual. One 32-lane group per (n,s).
__global__ void gather_k(const float* __restrict__ out4d,
                         const int* __restrict__ sample,
                         float* __restrict__ P32,
                         unsigned short* __restrict__ X) {
    int idx = blockIdx.x * blockDim.x + threadIdx.x;   // 0 .. N*S*32-1
    int lane = idx & 31;
    int ns = idx >> 5;
    int nn = ns >> 13;
    int s  = ns & (S - 1);
    int smp = sample[s];
    int row = smp / WC;
    int col = smp - row * WC;
    const float* base = out4d + ((size_t)nn * C) * H * W
                      + (size_t)(PADC + row) * W + (PADC + col);
    float v = 0.f;
    if (lane < C) v = base[(size_t)lane * (H * W)];
    unsigned short hb = f2bf_rne(v);
    float hf = bf2f(hb);
    unsigned short lb = f2bf_rne(v - hf);

    if (lane < CP) P32[(size_t)ns * CP + lane] = v;     // lane 19 writes 0
    unsigned short* xr = X + (size_t)ns * XP;
    xr[lane]      = hb;   // lanes >=19: v==0 -> 0
    xr[32 + lane] = lb;
}

// per (n, s-tile-of-32 x8 waves, t-chunk): best sim + lowest t, via bf16
// split-precision MFMA. D[t][s]: col=lane&31 -> s, rows in 16 acc regs -> t.
__global__ __launch_bounds__(512, 4) void argmax_k(const unsigned short* __restrict__ X,
                                                   float* __restrict__ pmax,
                                                   int* __restrict__ pidx) {
    __shared__ unsigned short lds[2][TTS * LPITCH];   // 2 x 18432 B
    int b = blockIdx.x;
    int chunk  = b & (NCHUNK - 1);
    int sgroup = (b >> 3) & 31;       // 32 s-groups of 8 tiles
    int nn     = b >> 8;
    int tid  = threadIdx.x;
    int w    = tid >> 6;              // wave 0..7 -> s-tile within group
    int lane = tid & 63;
    int col  = lane & 31;
    int hi   = lane >> 5;
    int s0   = (sgroup * 8 + w) * 32;
    int t0   = chunk * CHUNKT;
    const unsigned short* Xn = X + (size_t)nn * S * XP;

    // B-frags (s operand), loop-invariant: lane reads 8 k-slots at
    // kb + hi*8 for kb in {0,16,32,48}
    short8 bf[4];
    {
        const unsigned short* brow = Xn + (size_t)(s0 + col) * XP + hi * 8;
        bf[0] = *(const short8*)(brow +  0);
        bf[1] = *(const short8*)(brow + 16);
        bf[2] = *(const short8*)(brow + 32);
        bf[3] = *(const short8*)(brow + 48);
    }

    f32x16 zacc = {};   // stays zero: mfma C-operand for fresh tiles
    float best[16];
    int   bt[16];
    #pragma unroll
    for (int r = 0; r < 16; ++r) { best[r] = -INFINITY; bt[r] = 0; }

    // staging map: float4 f in [0,1024): row=f>>3, u16slot j=f&7
    int r0 = tid >> 3, j0 = tid & 7;
    int r1 = (tid + 512) >> 3;

    // prologue: stage 0
    {
        const float4* src = (const float4*)(Xn + (size_t)t0 * XP);
        float4 sa = src[tid], sb = src[tid + 512];
        *(float4*)(&lds[0][r0 * LPITCH + j0 * 8]) = sa;
        *(float4*)(&lds[0][r1 * LPITCH + j0 * 8]) = sb;
    }
    __syncthreads();

    int cur = 0;
    for (int st = 0; st < CHUNKT / TTS; ++st) {
        float4 na, nb;
        if (st < CHUNKT / TTS - 1) {
            const float4* srcn = (const float4*)(Xn + (size_t)(t0 + (st + 1) * TTS) * XP);
            na = srcn[tid]; nb = srcn[tid + 512];
        }
        const unsigned short* bs = &lds[cur][0];
        #pragma unroll
        for (int ts = 0; ts < TTS / 32; ++ts) {
            const unsigned short* arow = bs + (size_t)(ts * 32 + col) * LPITCH + hi * 8;
            short8 a0 = *(const short8*)(arow +  0);
            short8 a1 = *(const short8*)(arow + 16);
            short8 a2 = *(const short8*)(arow + 32);
            short8 a3 = *(const short8*)(arow + 48);
            f32x16 acc = __builtin_amdgcn_mfma_f32_32x32x16_bf16(a0, bf[0], zacc, 0, 0, 0);
            acc = __builtin_amdgcn_mfma_f32_32x32x16_bf16(a1, bf[1], acc, 0, 0, 0); // hi.hi
            acc = __builtin_amdgcn_mfma_f32_32x32x16_bf16(a0, bf[2], acc, 0, 0, 0);
            acc = __builtin_amdgcn_mfma_f32_32x32x16_bf16(a1, bf[3], acc, 0, 0, 0); // hi.lo
            acc = __builtin_amdgcn_mfma_f32_32x32x16_bf16(a2, bf[0], acc, 0, 0, 0);
            acc = __builtin_amdgcn_mfma_f32_32x32x16_bf16(a3, bf[1], acc, 0, 0, 0); // lo.hi
            int tile = st * (TTS / 32) + ts;          // [0,32)
            #pragma unroll
            for (int r = 0; r < 16; ++r) {
                float d = acc[r];
                if (d > best[r]) { best[r] = d; bt[r] = tile; }  // strict >: earliest tile
            }
        }
        __syncthreads();
        if (st < CHUNKT / TTS - 1) {
            *(float4*)(&lds[cur ^ 1][r0 * LPITCH + j0 * 8]) = na;
            *(float4*)(&lds[cur ^ 1][r1 * LPITCH + j0 * 8]) = nb;
            cur ^= 1;
            __syncthreads();
        }
    }

    // resolve 16 slots (value desc, then t asc), then merge lane-halves
    float B = -INFINITY; int Bt = 0x7fffffff;
    #pragma unroll
    for (int r = 0; r < 16; ++r) {
        int t = t0 + bt[r] * 32 + ((r & 3) + 8 * (r >> 2) + 4 * hi);
        if (best[r] > B || (best[r] == B && t < Bt)) { B = best[r]; Bt = t; }
    }
    float pB  = __shfl(B,  lane ^ 32, 64);
    int   pBt = __shfl(Bt, lane ^ 32, 64);
    if (pB > B || (pB == B && pBt < Bt)) { B = pB; Bt = pBt; }
    if (lane < 32) {
        int s = s0 + lane;
        pmax[((size_t)nn * NCHUNK + chunk) * S + s] = B;
        pidx[((size_t)nn * NCHUNK + chunk) * S + s] = Bt;
    }
}

// merge chunk partials -> ind, then the 19 loss terms; fixed-order block reduce
__global__ __launch_bounds__(256) void loss_k(const float* __restrict__ P32,
                                              const float* __restrict__ pmax,
                                              const int* __restrict__ pidx,
                                              float* __restrict__ bsum) {
    __shared__ float red[256];
    int idx = blockIdx.x * 256 + threadIdx.x;   // 0 .. N*S-1
    int nn = idx / S;
    int s  = idx - nn * S;

    const float* pm = pmax + (size_t)nn * NCHUNK * S + s;
    const int*   pi = pidx + (size_t)nn * NCHUNK * S + s;
    float best = pm[0];
    int bi = pi[0];
    #pragma unroll
    for (int k = 1; k < NCHUNK; ++k) {
        float v = pm[(size_t)k * S];
        int   t = pi[(size_t)k * S];
        if (v > best) { best = v; bi = t; }   // ascending chunks: first-max wins
    }

    const float* Pn   = P32 + (size_t)nn * S * CP;
    const float* nrow = Pn + (size_t)bi * CP;
    const float* ps   = Pn + (size_t)s  * CP;
    float acc = 0.f;
    #pragma unroll
    for (int c = 0; c < C; ++c) acc -= nrow[c] * logf(ps[c] + EPSF);

    red[threadIdx.x] = acc;
    __syncthreads();
    for (int off = 128; off > 0; off >>= 1) {
        if (threadIdx.x < off) red[threadIdx.x] += red[threadIdx.x + off];
        __syncthreads();
    }
    if (threadIdx.x == 0) bsum[blockIdx.x] = red[0];
}

__global__ void final_k(const float* __restrict__ bsum, float* __restrict__ out) {
    float t = 0.f;
    for (int i = 0; i < (N * S) / 256; ++i) t += bsum[i];   // fixed order
    out[0] = t / (float)(N * S * C);
}

extern "C" void kernel_launch(void* const* d_in, const int* in_sizes, int n_in,
                              void* d_out, int out_size, void* d_ws, size_t ws_size,
                              hipStream_t stream) {
    const float* out4d  = (const float*)d_in[0];
    const int*   sample = (const int*)d_in[1];

    float*          P32  = (float*)d_ws;                          // N*S*CP floats
    unsigned short* X    = (unsigned short*)(P32 + (size_t)N * S * CP); // N*S*XP u16
    float*          pmax = (float*)(X + (size_t)N * S * XP);      // N*NCHUNK*S floats
    int*            pidx = (int*)(pmax + (size_t)N * NCHUNK * S); // N*NCHUNK*S ints
    float*          bsum = (float*)(pidx + (size_t)N * NCHUNK * S); // 64 floats
    float*          outp = (float*)d_out;

    gather_k<<<(N * S * 32) / 256, 256, 0, stream>>>(out4d, sample, P32, X);
    argmax_k<<<N * 32 * NCHUNK, 512, 0, stream>>>(X, pmax, pidx);
    loss_k<<<(N * S) / 256, 256, 0, stream>>>(P32, pmax, pidx, bsum);
    final_k<<<1, 1, 0, stream>>>(bsum, outp);
}

// Round 6
// 43.060 us; speedup vs baseline: 2.5879x; 1.2305x over previous
//
#include <hip/hip_runtime.h>
#include <math.h>

#define N 2
#define C 19
#define H 512
#define W 512
#define PADC 50
#define WC 412
#define S 8192
#define CP 20            // fp32 P row pitch (floats)
#define XP 64            // bf16 X row pitch (ushorts): hi 0..31, lo 32..63
#define NCHUNK 16
#define CHUNKT (S / NCHUNK)      // 512 t per chunk
#define TTS 128                  // t rows per LDS stage
#define NSTG (CHUNKT / TTS)      // 4
#define TPS (TTS / 32)           // tiles per stage = 4
#define LPITCH 72                // ushorts per LDS row (144 B)
#define EPSF 1e-6f

typedef __attribute__((ext_vector_type(8))) short short8;
typedef __attribute__((ext_vector_type(16))) float f32x16;

__device__ __forceinline__ unsigned short f2bf_rne(float x) {
    unsigned u = __float_as_uint(x);
    unsigned r = (u + 0x7FFFu + ((u >> 16) & 1u)) >> 16;
    return (unsigned short)r;
}
__device__ __forceinline__ float bf2f(unsigned short h) {
    return __uint_as_float(((unsigned)h) << 16);
}
__device__ __forceinline__ float max16(const f32x16 a) {
    float m0 = fmaxf(a[0], a[1]),   m1 = fmaxf(a[2], a[3]);
    float m2 = fmaxf(a[4], a[5]),   m3 = fmaxf(a[6], a[7]);
    float m4 = fmaxf(a[8], a[9]),   m5 = fmaxf(a[10], a[11]);
    float m6 = fmaxf(a[12], a[13]), m7 = fmaxf(a[14], a[15]);
    m0 = fmaxf(m0, m1); m2 = fmaxf(m2, m3);
    m4 = fmaxf(m4, m5); m6 = fmaxf(m6, m7);
    m0 = fmaxf(m0, m2); m4 = fmaxf(m4, m6);
    return fmaxf(m0, m4);
}

// P32[n][s][c] fp32 (for loss/refine); X[n][s][0..31]=hi bf16, [32..63]=lo bf16.
__global__ void gather_k(const float* __restrict__ out4d,
                         const int* __restrict__ sample,
                         float* __restrict__ P32,
                         unsigned short* __restrict__ X) {
    int idx = blockIdx.x * blockDim.x + threadIdx.x;   // 0 .. N*S*32-1
    int lane = idx & 31;
    int ns = idx >> 5;
    int nn = ns >> 13;
    int s  = ns & (S - 1);
    int smp = sample[s];
    int row = smp / WC;
    int col = smp - row * WC;
    const float* base = out4d + ((size_t)nn * C) * H * W
                      + (size_t)(PADC + row) * W + (PADC + col);
    float v = 0.f;
    if (lane < C) v = base[(size_t)lane * (H * W)];
    unsigned short hb = f2bf_rne(v);
    float hf = bf2f(hb);
    unsigned short lb = f2bf_rne(v - hf);

    if (lane < CP) P32[(size_t)ns * CP + lane] = v;     // lane 19 writes 0
    unsigned short* xr = X + (size_t)ns * XP;
    xr[lane]      = hb;
    xr[32 + lane] = lb;
}

// per (n, 512-s-group, t-chunk): per-s best (quantized sim, earliest tile) as a
// packed u32 key. Each wave owns TWO 32-s tiles -> 12 MFMA per 4 ds_read_b128.
__global__ __launch_bounds__(512, 4) void argmax_k(const unsigned short* __restrict__ X,
                                                   unsigned* __restrict__ keys) {
    __shared__ unsigned short lds[2][TTS * LPITCH];   // 2 x 18432 B
    int b = blockIdx.x;
    int chunk  = b & (NCHUNK - 1);
    int sgroup = (b >> 4) & 15;
    int nn     = b >> 8;
    int tid  = threadIdx.x;
    int w    = tid >> 6;
    int lane = tid & 63;
    int col  = lane & 31;
    int hi   = lane >> 5;
    int s0   = (sgroup * 16 + w) * 32;   // B-set A
    int s1   = s0 + 256;                 // B-set B (tile w+8)
    int t0   = chunk * CHUNKT;
    const unsigned short* Xn = X + (size_t)nn * S * XP;

    short8 bfA[4], bfB[4];
    {
        const unsigned short* ba = Xn + (size_t)(s0 + col) * XP + hi * 8;
        bfA[0] = *(const short8*)(ba);      bfA[1] = *(const short8*)(ba + 16);
        bfA[2] = *(const short8*)(ba + 32); bfA[3] = *(const short8*)(ba + 48);
        const unsigned short* bb = Xn + (size_t)(s1 + col) * XP + hi * 8;
        bfB[0] = *(const short8*)(bb);      bfB[1] = *(const short8*)(bb + 16);
        bfB[2] = *(const short8*)(bb + 32); bfB[3] = *(const short8*)(bb + 48);
    }

    f32x16 zacc = {};
    unsigned kA = 0u, kB = 0u;

    int r0 = tid >> 3, j0 = tid & 7;
    int r1 = r0 + 64;

    {   // prologue: stage 0 -> buf0 (128 rows x 128 B)
        const float4* src = (const float4*)(Xn + (size_t)t0 * XP);
        *(float4*)(&lds[0][r0 * LPITCH + j0 * 8]) = src[tid];
        *(float4*)(&lds[0][r1 * LPITCH + j0 * 8]) = src[tid + 512];
    }
    __syncthreads();

    int cur = 0;
    for (int st = 0; st < NSTG; ++st) {
        float4 na, nb;
        if (st + 1 < NSTG) {   // issue next-stage loads early
            const float4* srcn = (const float4*)(Xn + (size_t)(t0 + (st + 1) * TTS) * XP);
            na = srcn[tid]; nb = srcn[tid + 512];
        }
        const unsigned short* bs = &lds[cur][0];
        #pragma unroll
        for (int ts = 0; ts < TPS; ++ts) {
            const unsigned short* arow = bs + (ts * 32 + col) * LPITCH + hi * 8;
            short8 a0 = *(const short8*)(arow);
            short8 a1 = *(const short8*)(arow + 16);
            short8 a2 = *(const short8*)(arow + 32);
            short8 a3 = *(const short8*)(arow + 48);
            f32x16 accA = __builtin_amdgcn_mfma_f32_32x32x16_bf16(a0, bfA[0], zacc, 0, 0, 0);
            accA = __builtin_amdgcn_mfma_f32_32x32x16_bf16(a1, bfA[1], accA, 0, 0, 0); // hi.hi
            accA = __builtin_amdgcn_mfma_f32_32x32x16_bf16(a0, bfA[2], accA, 0, 0, 0);
            accA = __builtin_amdgcn_mfma_f32_32x32x16_bf16(a1, bfA[3], accA, 0, 0, 0); // hi.lo
            accA = __builtin_amdgcn_mfma_f32_32x32x16_bf16(a2, bfA[0], accA, 0, 0, 0);
            accA = __builtin_amdgcn_mfma_f32_32x32x16_bf16(a3, bfA[1], accA, 0, 0, 0); // lo.hi
            f32x16 accB = __builtin_amdgcn_mfma_f32_32x32x16_bf16(a0, bfB[0], zacc, 0, 0, 0);
            accB = __builtin_amdgcn_mfma_f32_32x32x16_bf16(a1, bfB[1], accB, 0, 0, 0);
            accB = __builtin_amdgcn_mfma_f32_32x32x16_bf16(a0, bfB[2], accB, 0, 0, 0);
            accB = __builtin_amdgcn_mfma_f32_32x32x16_bf16(a1, bfB[3], accB, 0, 0, 0);
            accB = __builtin_amdgcn_mfma_f32_32x32x16_bf16(a2, bfB[0], accB, 0, 0, 0);
            accB = __builtin_amdgcn_mfma_f32_32x32x16_bf16(a3, bfB[1], accB, 0, 0, 0);
            int tile = st * TPS + ts;              // [0,16)
            unsigned tb = (unsigned)(63 - tile);   // larger = earlier tile
            float mA = fmaxf(max16(accA), 0.f);
            float mB = fmaxf(max16(accB), 0.f);
            unsigned vA = (__float_as_uint(mA) & ~63u) | tb;
            unsigned vB = (__float_as_uint(mB) & ~63u) | tb;
            kA = kA > vA ? kA : vA;
            kB = kB > vB ? kB : vB;
        }
        if (st + 1 < NSTG) {   // write other buffer after compute; 1 barrier/stage
            *(float4*)(&lds[cur ^ 1][r0 * LPITCH + j0 * 8]) = na;
            *(float4*)(&lds[cur ^ 1][r1 * LPITCH + j0 * 8]) = nb;
        }
        __syncthreads();
        cur ^= 1;
    }

    // merge lane halves (same tile-id bits -> plain u32 max is safe)
    unsigned oA = __shfl(kA, lane ^ 32, 64);
    unsigned oB = __shfl(kB, lane ^ 32, 64);
    kA = kA > oA ? kA : oA;
    kB = kB > oB ? kB : oB;
    if (lane < 32) {
        size_t basek = ((size_t)nn * NCHUNK + chunk) * S;
        keys[basek + s0 + col] = kA;
        keys[basek + s1 + col] = kB;
    }
}

// per s: merge chunk keys (ascending, strict > on quantized value -> earliest
// chunk), then EXACT fp32 rescan of the winning 32-row tile, first-max.
__global__ __launch_bounds__(256) void refine_k(const float* __restrict__ P32,
                                                const unsigned* __restrict__ keys,
                                                int* __restrict__ ind) {
    int tid = threadIdx.x;
    int wv = blockIdx.x * 4 + (tid >> 6);   // 2 s per wave
    int lane = tid & 63;
    int hi = lane >> 5;
    int l  = lane & 31;
    int ns = wv * 2 + hi;                   // 0 .. N*S-1
    int nn = ns >> 13;
    int s  = ns & (S - 1);

    const unsigned* kp = keys + (size_t)nn * NCHUNK * S + s;
    unsigned bk = kp[0]; int bc = 0;
    #pragma unroll
    for (int c = 1; c < NCHUNK; ++c) {
        unsigned k = kp[(size_t)c * S];
        if ((k >> 6) > (bk >> 6)) { bk = k; bc = c; }
    }
    int tile = 63 - (int)(bk & 63u);
    int tbase = bc * CHUNKT + tile * 32;

    const float* Pn = P32 + (size_t)nn * S * CP;
    const float* sr = Pn + (size_t)s * CP;
    const float* tr = Pn + (size_t)(tbase + l) * CP;
    float v = 0.f;
    #pragma unroll
    for (int c = 0; c < C; ++c) v = fmaf(sr[c], tr[c], v);
    int t = tbase + l;
    #pragma unroll
    for (int off = 16; off > 0; off >>= 1) {
        float ov = __shfl_xor(v, off, 32);
        int   ot = __shfl_xor(t, off, 32);
        if (ov > v || (ov == v && ot < t)) { v = ov; t = ot; }  // first-max
    }
    if (l == 0) ind[ns] = t;
}

// 19 loss terms per s; fixed-order block reduce
__global__ __launch_bounds__(256) void loss_k(const float* __restrict__ P32,
                                              const int* __restrict__ ind,
                                              float* __restrict__ bsum) {
    __shared__ float red[256];
    int idx = blockIdx.x * 256 + threadIdx.x;   // 0 .. N*S-1
    int nn = idx >> 13;
    int s  = idx & (S - 1);
    int bi = ind[idx];

    const float* Pn   = P32 + (size_t)nn * S * CP;
    const float* nrow = Pn + (size_t)bi * CP;
    const float* ps   = Pn + (size_t)s  * CP;
    float acc = 0.f;
    #pragma unroll
    for (int c = 0; c < C; ++c) acc -= nrow[c] * logf(ps[c] + EPSF);

    red[threadIdx.x] = acc;
    __syncthreads();
    for (int off = 128; off > 0; off >>= 1) {
        if (threadIdx.x < off) red[threadIdx.x] += red[threadIdx.x + off];
        __syncthreads();
    }
    if (threadIdx.x == 0) bsum[blockIdx.x] = red[0];
}

__global__ void final_k(const float* __restrict__ bsum, float* __restrict__ out) {
    float t = 0.f;
    for (int i = 0; i < (N * S) / 256; ++i) t += bsum[i];   // fixed order
    out[0] = t / (float)(N * S * C);
}

extern "C" void kernel_launch(void* const* d_in, const int* in_sizes, int n_in,
                              void* d_out, int out_size, void* d_ws, size_t ws_size,
                              hipStream_t stream) {
    const float* out4d  = (const float*)d_in[0];
    const int*   sample = (const int*)d_in[1];

    float*          P32  = (float*)d_ws;                               // N*S*CP f32
    unsigned short* X    = (unsigned short*)(P32 + (size_t)N * S * CP); // N*S*XP u16
    unsigned*       keys = (unsigned*)(X + (size_t)N * S * XP);        // N*NCHUNK*S u32
    int*            ind  = (int*)(keys + (size_t)N * NCHUNK * S);      // N*S int
    float*          bsum = (float*)(ind + (size_t)N * S);              // 64 f32
    float*          outp = (float*)d_out;

    gather_k<<<(N * S * 32) / 256, 256, 0, stream>>>(out4d, sample, P32, X);
    argmax_k<<<N * 16 * NCHUNK, 512, 0, stream>>>(X, keys);
    refine_k<<<(N * S) / 8, 256, 0, stream>>>(P32, keys, ind);
    loss_k<<<(N * S) / 256, 256, 0, stream>>>(P32, ind, bsum);
    final_k<<<1, 1, 0, stream>>>(bsum, outp);
}

// Round 7
// 36.202 us; speedup vs baseline: 3.0782x; 1.1894x over previous
//
#include <hip/hip_runtime.h>
#include <math.h>

#define N 2
#define C 19
#define H 512
#define W 512
#define PADC 50
#define WC 412
#define S 8192
#define CP 20            // fp32 P row pitch (floats)
#define XP 64            // packed row pitch (ushorts): two 32-slot K-vectors
#define NCHUNK 16
#define CHUNKT (S / NCHUNK)      // 512 t per chunk
#define TTS 128                  // t rows per LDS stage
#define NSTG (CHUNKT / TTS)      // 4
#define TPS (TTS / 32)           // tiles per stage = 4
#define LPITCH 72                // ushorts per LDS row (144 B)
#define EPSF 1e-6f

typedef __attribute__((ext_vector_type(8))) short short8;
typedef __attribute__((ext_vector_type(16))) float f32x16;

__device__ __forceinline__ unsigned short f2bf_rne(float x) {
    unsigned u = __float_as_uint(x);
    unsigned r = (u + 0x7FFFu + ((u >> 16) & 1u)) >> 16;
    return (unsigned short)r;
}
__device__ __forceinline__ float bf2f(unsigned short h) {
    return __uint_as_float(((unsigned)h) << 16);
}
// max of 16 accs, clamped >= 0; max3-shaped (5+2+1 = 8 ops)
__device__ __forceinline__ float max16c(const f32x16 a) {
    float m0 = fmaxf(fmaxf(a[0], a[1]), a[2]);
    float m1 = fmaxf(fmaxf(a[3], a[4]), a[5]);
    float m2 = fmaxf(fmaxf(a[6], a[7]), a[8]);
    float m3 = fmaxf(fmaxf(a[9], a[10]), a[11]);
    float m4 = fmaxf(fmaxf(a[12], a[13]), a[14]);
    float n0 = fmaxf(fmaxf(m0, m1), m2);
    float n1 = fmaxf(fmaxf(m3, m4), a[15]);
    return fmaxf(fmaxf(n0, n1), 0.f);
}

// P32: exact fp32 rows. XA/XB: packed split-precision K=2x32 layouts so that
// slot-wise A*B gives hi.hi(19) + hi.lo(19) + lo.hi(19) (57 products in 64 slots):
//  A row: [hi(0..18), lo(0..12) | hi(0..18), lo(13..18), 0*7]
//  B row: [hi(0..18), hi(0..12) | lo(0..18), hi(13..18), 0*7]
__global__ void gather_k(const float* __restrict__ out4d,
                         const int* __restrict__ sample,
                         float* __restrict__ P32,
                         unsigned short* __restrict__ XA,
                         unsigned short* __restrict__ XB) {
    int idx = blockIdx.x * blockDim.x + threadIdx.x;   // 0 .. N*S*32-1
    int lane = idx & 63;
    int hi   = lane >> 5;
    int l    = lane & 31;
    int ns = idx >> 5;
    int nn = ns >> 13;
    int s  = ns & (S - 1);
    int smp = sample[s];
    int row = smp / WC;
    int col = smp - row * WC;
    const float* base = out4d + ((size_t)nn * C) * H * W
                      + (size_t)(PADC + row) * W + (PADC + col);
    float v = 0.f;
    if (l < C) v = base[(size_t)l * (H * W)];
    unsigned hb = f2bf_rne(v);
    unsigned lb = f2bf_rne(v - bf2f((unsigned short)hb));

    if (l < CP) P32[(size_t)ns * CP + l] = v;          // l==19 writes 0

    int base32 = hi << 5;
    int srcA = base32 + (l < C ? l : l - C);           // channel l-19 for tail
    int srcB = base32 + (l < C ? l : l - 6);           // channel l-6  for tail
    unsigned lbA = (unsigned)__shfl((int)lb, srcA, 64);
    unsigned hbA = (unsigned)__shfl((int)hb, srcA, 64);
    unsigned lbB = (unsigned)__shfl((int)lb, srcB, 64);
    unsigned hbB = (unsigned)__shfl((int)hb, srcB, 64);

    unsigned short a0 = (unsigned short)(l < C ? hb : lbA);                   // slot I
    unsigned short a1 = (unsigned short)(l < C ? hb : (l < 25 ? lbB : 0u));   // slot II
    unsigned short b0 = (unsigned short)hbA;                                  // slot I
    unsigned short b1 = (unsigned short)(l < C ? lb : (l < 25 ? hbB : 0u));   // slot II

    unsigned short* xa = XA + (size_t)ns * XP;
    unsigned short* xb = XB + (size_t)ns * XP;
    xa[l]      = a0;
    xa[32 + l] = a1;
    xb[l]      = b0;
    xb[32 + l] = b1;
}

// per (n, 512-s-group, t-chunk): per-s best (quantized sim, earliest tile) as a
// packed u32 key. Each wave owns TWO 32-s tiles -> 8 MFMA per 4 ds_read_b128.
__global__ __launch_bounds__(512, 4) void argmax_k(const unsigned short* __restrict__ XA,
                                                   const unsigned short* __restrict__ XB,
                                                   unsigned* __restrict__ keys) {
    __shared__ unsigned short lds[2][TTS * LPITCH];   // 2 x 18432 B
    int b = blockIdx.x;
    int chunk  = b & (NCHUNK - 1);
    int sgroup = (b >> 4) & 15;
    int nn     = b >> 8;
    int tid  = threadIdx.x;
    int w    = tid >> 6;
    int lane = tid & 63;
    int col  = lane & 31;
    int hi   = lane >> 5;
    int s0   = (sgroup * 16 + w) * 32;   // B-set A
    int s1   = s0 + 256;                 // B-set B
    int t0   = chunk * CHUNKT;
    const unsigned short* XAn = XA + (size_t)nn * S * XP;
    const unsigned short* XBn = XB + (size_t)nn * S * XP;

    short8 bfA[4], bfB[4];
    {
        const unsigned short* ba = XBn + (size_t)(s0 + col) * XP + hi * 8;
        bfA[0] = *(const short8*)(ba);      bfA[1] = *(const short8*)(ba + 16);
        bfA[2] = *(const short8*)(ba + 32); bfA[3] = *(const short8*)(ba + 48);
        const unsigned short* bb = XBn + (size_t)(s1 + col) * XP + hi * 8;
        bfB[0] = *(const short8*)(bb);      bfB[1] = *(const short8*)(bb + 16);
        bfB[2] = *(const short8*)(bb + 32); bfB[3] = *(const short8*)(bb + 48);
    }

    f32x16 zacc = {};
    unsigned kA = 0u, kB = 0u;

    int r0 = tid >> 3, j0 = tid & 7;
    int r1 = r0 + 64;

    {   // prologue: stage 0 -> buf0 (128 rows x 128 B)
        const float4* src = (const float4*)(XAn + (size_t)t0 * XP);
        *(float4*)(&lds[0][r0 * LPITCH + j0 * 8]) = src[tid];
        *(float4*)(&lds[0][r1 * LPITCH + j0 * 8]) = src[tid + 512];
    }
    __syncthreads();

    int cur = 0;
    for (int st = 0; st < NSTG; ++st) {
        float4 na, nb;
        if (st + 1 < NSTG) {   // issue next-stage loads early
            const float4* srcn = (const float4*)(XAn + (size_t)(t0 + (st + 1) * TTS) * XP);
            na = srcn[tid]; nb = srcn[tid + 512];
        }
        const unsigned short* bs = &lds[cur][0];
        #pragma unroll
        for (int ts = 0; ts < TPS; ++ts) {
            const unsigned short* arow = bs + (ts * 32 + col) * LPITCH + hi * 8;
            short8 a0 = *(const short8*)(arow);
            short8 a1 = *(const short8*)(arow + 16);
            short8 a2 = *(const short8*)(arow + 32);
            short8 a3 = *(const short8*)(arow + 48);
            f32x16 accA = __builtin_amdgcn_mfma_f32_32x32x16_bf16(a0, bfA[0], zacc, 0, 0, 0);
            accA = __builtin_amdgcn_mfma_f32_32x32x16_bf16(a1, bfA[1], accA, 0, 0, 0);
            accA = __builtin_amdgcn_mfma_f32_32x32x16_bf16(a2, bfA[2], accA, 0, 0, 0);
            accA = __builtin_amdgcn_mfma_f32_32x32x16_bf16(a3, bfA[3], accA, 0, 0, 0);
            f32x16 accB = __builtin_amdgcn_mfma_f32_32x32x16_bf16(a0, bfB[0], zacc, 0, 0, 0);
            accB = __builtin_amdgcn_mfma_f32_32x32x16_bf16(a1, bfB[1], accB, 0, 0, 0);
            accB = __builtin_amdgcn_mfma_f32_32x32x16_bf16(a2, bfB[2], accB, 0, 0, 0);
            accB = __builtin_amdgcn_mfma_f32_32x32x16_bf16(a3, bfB[3], accB, 0, 0, 0);
            int tile = st * TPS + ts;              // [0,16)
            unsigned tb = (unsigned)(63 - tile);   // larger = earlier tile
            unsigned vA = (__float_as_uint(max16c(accA)) & ~63u) | tb;
            unsigned vB = (__float_as_uint(max16c(accB)) & ~63u) | tb;
            kA = kA > vA ? kA : vA;
            kB = kB > vB ? kB : vB;
        }
        if (st + 1 < NSTG) {   // write other buffer after compute; 1 barrier/stage
            *(float4*)(&lds[cur ^ 1][r0 * LPITCH + j0 * 8]) = na;
            *(float4*)(&lds[cur ^ 1][r1 * LPITCH + j0 * 8]) = nb;
        }
        __syncthreads();
        cur ^= 1;
    }

    unsigned oA = __shfl(kA, lane ^ 32, 64);
    unsigned oB = __shfl(kB, lane ^ 32, 64);
    kA = kA > oA ? kA : oA;
    kB = kB > oB ? kB : oB;
    if (lane < 32) {
        size_t basek = ((size_t)nn * NCHUNK + chunk) * S;
        keys[basek + s0 + col] = kA;
        keys[basek + s1 + col] = kB;
    }
}

// per s: merge chunk keys (earliest chunk on quantized ties), EXACT fp32 rescan
// of the winning 32-row tile (first-max), then the 19 loss terms; fixed-order
// reductions -> one partial per block.
__global__ __launch_bounds__(256) void refine_loss_k(const float* __restrict__ P32,
                                                     const unsigned* __restrict__ keys,
                                                     float* __restrict__ bsum) {
    __shared__ float red[8];
    int tid = threadIdx.x;
    int lane = tid & 63;
    int hi = lane >> 5;
    int l  = lane & 31;
    int ns = blockIdx.x * 8 + (tid >> 6) * 2 + hi;   // 0 .. N*S-1
    int nn = ns >> 13;
    int s  = ns & (S - 1);

    const unsigned* kp = keys + (size_t)nn * NCHUNK * S + s;
    unsigned bk = kp[0]; int bc = 0;
    #pragma unroll
    for (int c = 1; c < NCHUNK; ++c) {
        unsigned k = kp[(size_t)c * S];
        if ((k >> 6) > (bk >> 6)) { bk = k; bc = c; }
    }
    int tile = 63 - (int)(bk & 63u);
    int tbase = bc * CHUNKT + tile * 32;

    const float* Pn = P32 + (size_t)nn * S * CP;
    const float* sr = Pn + (size_t)s * CP;
    const float* tr = Pn + (size_t)(tbase + l) * CP;
    float v = 0.f;
    #pragma unroll
    for (int c = 0; c < C; ++c) v = fmaf(sr[c], tr[c], v);
    int t = tbase + l;
    #pragma unroll
    for (int off = 16; off > 0; off >>= 1) {
        float ov = __shfl_xor(v, off, 32);
        int   ot = __shfl_xor(t, off, 32);
        if (ov > v || (ov == v && ot < t)) { v = ov; t = ot; }  // first-max
    }
    // all 32 lanes now hold t*; lanes 0..18 each compute one loss term
    const float* nrow = Pn + (size_t)t * CP;
    float term = 0.f;
    if (l < C) term = -nrow[l] * logf(sr[l] + EPSF);
    #pragma unroll
    for (int off = 16; off > 0; off >>= 1)
        term += __shfl_xor(term, off, 32);
    if (l == 0) red[tid >> 5] = term;
    __syncthreads();
    if (tid == 0) {
        float a = 0.f;
        #pragma unroll
        for (int i = 0; i < 8; ++i) a += red[i];    // fixed order
        bsum[blockIdx.x] = a;
    }
}

// 2048 partials -> scalar; fixed-order tree
__global__ __launch_bounds__(256) void final_k(const float* __restrict__ bsum,
                                               float* __restrict__ out) {
    __shared__ float red[256];
    int tid = threadIdx.x;
    float a = 0.f;
    #pragma unroll
    for (int i = 0; i < 8; ++i) a += bsum[i * 256 + tid];   // fixed order
    red[tid] = a;
    __syncthreads();
    for (int off = 128; off > 0; off >>= 1) {
        if (tid < off) red[tid] += red[tid + off];
        __syncthreads();
    }
    if (tid == 0) out[0] = red[0] / (float)(N * S * C);
}

extern "C" void kernel_launch(void* const* d_in, const int* in_sizes, int n_in,
                              void* d_out, int out_size, void* d_ws, size_t ws_size,
                              hipStream_t stream) {
    const float* out4d  = (const float*)d_in[0];
    const int*   sample = (const int*)d_in[1];

    float*          P32  = (float*)d_ws;                                // N*S*CP f32
    unsigned short* XA   = (unsigned short*)(P32 + (size_t)N * S * CP); // N*S*XP u16
    unsigned short* XB   = XA + (size_t)N * S * XP;                     // N*S*XP u16
    unsigned*       keys = (unsigned*)(XB + (size_t)N * S * XP);        // N*NCHUNK*S u32
    float*          bsum = (float*)(keys + (size_t)N * NCHUNK * S);     // 2048 f32
    float*          outp = (float*)d_out;

    gather_k<<<(N * S * 32) / 256, 256, 0, stream>>>(out4d, sample, P32, XA, XB);
    argmax_k<<<N * 16 * NCHUNK, 512, 0, stream>>>(XA, XB, keys);
    refine_loss_k<<<(N * S) / 8, 256, 0, stream>>>(P32, keys, bsum);
    final_k<<<1, 256, 0, stream>>>(bsum, outp);
}